// Round 12
// baseline (475.133 us; speedup 1.0000x reference)
//
#include <hip/hip_runtime.h>
#include <hip/hip_bf16.h>
#include <math.h>

typedef short bf16x8 __attribute__((ext_vector_type(8)));
typedef float f32x4 __attribute__((ext_vector_type(4)));
typedef unsigned int u32;

#define B_DIM 8192
#define H_DIM 1024
#define NPATH 256
#define NSTEP 50

__device__ __forceinline__ void gld_lds16(const void* g, void* lds) {
  __builtin_amdgcn_global_load_lds(
      (const __attribute__((address_space(1))) u32*)g,
      (__attribute__((address_space(3))) u32*)lds, 16, 0, 0);
}

__device__ __forceinline__ void cast4(const float* in, __hip_bfloat16* out, int i) {
  float4 v = ((const float4*)in)[i];
  union { __hip_bfloat16 h[4]; short4 s; } u;
  u.h[0] = __float2bfloat16(v.x);
  u.h[1] = __float2bfloat16(v.y);
  u.h[2] = __float2bfloat16(v.z);
  u.h[3] = __float2bfloat16(v.w);
  ((short4*)out)[i] = u.s;
}

// ---------------- fused prep: pure data movement ----------------
// [0,8192) cast x ; [8192,11264) transpose W_in/W_hid/W_out ; [11264,11520) W_agg^T
__global__ __launch_bounds__(256) void prep_kernel(
    const float* __restrict__ x, const float* __restrict__ W_in,
    const float* __restrict__ W_hid, const float* __restrict__ W_out,
    const float* __restrict__ W_agg,
    __hip_bfloat16* __restrict__ xb, __hip_bfloat16* __restrict__ wtin,
    __hip_bfloat16* __restrict__ wthid, __hip_bfloat16* __restrict__ wtout,
    __hip_bfloat16* __restrict__ wtagg) {
  __shared__ float t[32][33];
  int bid = blockIdx.x, tid = threadIdx.x;
  if (bid < 8192) {
    cast4(x, xb, bid * 256 + tid);
    return;
  }
  int job = bid - 8192;
  const float* W; __hip_bfloat16* Wt; int R, C;
  if (job < 1024)      { W = W_in;  Wt = wtin;  R = 1024; C = 1024; }
  else if (job < 2048) { W = W_hid; Wt = wthid; R = 1024; C = 1024; job -= 1024; }
  else if (job < 3072) { W = W_out; Wt = wtout; R = 1024; C = 1024; job -= 2048; }
  else                 { W = W_agg; Wt = wtagg; R = 256;  C = 1024; job -= 3072; }
  int nTx = C / 32;
  int tX = job % nTx, tY = job / nTx;
  int tx = tid & 31, r4 = tid >> 5;
#pragma unroll
  for (int i = 0; i < 4; ++i) {
    int ty = r4 * 4 + i;
    t[ty][tx] = W[(size_t)(tY * 32 + ty) * C + tX * 32 + tx];
  }
  __syncthreads();
#pragma unroll
  for (int i = 0; i < 4; ++i) {
    int ty = r4 * 4 + i;
    Wt[(size_t)(tX * 32 + ty) * R + tY * 32 + tx] = __float2bfloat16(t[tx][ty]);
  }
}

// ------------- fused feedback + endpoints: per block = 4 batch rows -------------
__global__ __launch_bounds__(256) void fb_end_kernel(
    const __hip_bfloat16* __restrict__ h2b, const float* __restrict__ Wfb,
    const float* __restrict__ bfb, const float* __restrict__ ns,
    __hip_bfloat16* __restrict__ eb, float DI, float SQDT) {
  __shared__ float fv[4];
  int wid = threadIdx.x >> 6, lane = threadIdx.x & 63;
  int row = blockIdx.x * 4 + wid;
  const __hip_bfloat16* hrow = h2b + (size_t)row * H_DIM;
  float s = 0.f;
#pragma unroll
  for (int i = lane; i < H_DIM; i += 64) s += __bfloat162float(hrow[i]) * Wfb[i];
#pragma unroll
  for (int off = 32; off > 0; off >>= 1) s += __shfl_down(s, off);
  if (lane == 0) fv[wid] = 1.0f / (1.0f + expf(-(s + bfb[0])));
  __syncthreads();
#pragma unroll
  for (int w = 0; w < 4; ++w) {
    size_t i = (size_t)(blockIdx.x * 4 + w) * NPATH + threadIdx.x;
    eb[i] = __float2bfloat16(fv[w] * DI + SQDT * ns[i]);
  }
}

// -------- trunk stage: WAVE-LEVEL heterogeneous block (placement-independent) ---
// 512 blocks x 320 threads. Waves 0-3: 128x128 MFMA GEMM (relu->bf16) with 32
// barriers (16 K-iters x 2). Wave 4: streams this block's 2048 noise rows
// (512 x 2048 = R/2, full coverage — R11's bug was 1024/block) in 32 barrier
// intervals x 64 rows. Every CU hosts 8 MFMA waves + 2 streaming waves (m114
// overlap), independent of block->XCD placement. Barrier counts match.
__global__ __launch_bounds__(320) void stage_kernel(
    const __hip_bfloat16* __restrict__ A, const __hip_bfloat16* __restrict__ Bt,
    const float* __restrict__ bias, __hip_bfloat16* __restrict__ out,
    const float* __restrict__ noise, float* __restrict__ ns, int rowStart) {
  __shared__ __hip_bfloat16 As[128 * 64];
  __shared__ __hip_bfloat16 Bs[128 * 64];
  const int tid = threadIdx.x;
  const int wid = tid >> 6;
  const int gb = blockIdx.x;               // 512 tiles, bm-major
  const int bm = gb >> 3, bn = gb & 7;

  if (wid == 4) {
    // noise wave: 2048 rows, 32 intervals x (2 sub-chunks of 32 rows),
    // 2 lanes per row (12|13 float2 halves), shfl_xor combine.
    const int lane = tid & 63;
    const int half = lane & 1;
    const int rb = rowStart + gb * 2048 + (lane >> 1);
    const int j0 = half * 12, j1 = half ? 25 : 12;
    for (int it = 0; it < 32; ++it) {
#pragma unroll
      for (int rep = 0; rep < 2; ++rep) {
        int row = rb + it * 64 + rep * 32;
        const float2* p = (const float2*)(noise + (size_t)row * NSTEP);
        float s = 0.f;
#pragma unroll
        for (int j = j0; j < j1; ++j) { float2 v = p[j]; s += v.x + v.y; }
        s += __shfl_xor(s, 1);
        if (!half) ns[row] = s;
      }
      __syncthreads();   // pairs with the GEMM waves' per-iter barriers
    }
    return;  // 32 barriers executed
  }

  // ---- GEMM waves (tid in [0,256)) ----
  const int lane = tid & 63;
  const int wr = wid >> 1, wc = wid & 1;
  const int frow = lane & 15, kgrp = lane >> 4;

  f32x4 acc[4][4];
#pragma unroll
  for (int m = 0; m < 4; ++m)
#pragma unroll
    for (int n = 0; n < 4; ++n) acc[m][n] = (f32x4){0.f, 0.f, 0.f, 0.f};

  for (int kt = 0; kt < H_DIM; kt += 64) {
#pragma unroll
    for (int r = 0; r < 4; ++r) {
      int c = r * 256 + tid;
      int row = c >> 3, cc = c & 7;
      gld_lds16((const char*)(A + (size_t)(bm * 128 + row) * H_DIM + kt) + cc * 16,
                (char*)As + c * 16);
      gld_lds16((const char*)(Bt + (size_t)(bn * 128 + row) * H_DIM + kt) + cc * 16,
                (char*)Bs + c * 16);
    }
    __syncthreads();
#pragma unroll
    for (int kk = 0; kk < 64; kk += 32) {
      bf16x8 af[4], bfr[4];
#pragma unroll
      for (int m = 0; m < 4; ++m)
        af[m] = *(const bf16x8*)(As + (wr * 64 + m * 16 + frow) * 64 + kk + kgrp * 8);
#pragma unroll
      for (int n = 0; n < 4; ++n)
        bfr[n] = *(const bf16x8*)(Bs + (wc * 64 + n * 16 + frow) * 64 + kk + kgrp * 8);
#pragma unroll
      for (int m = 0; m < 4; ++m)
#pragma unroll
        for (int n = 0; n < 4; ++n)
          acc[m][n] = __builtin_amdgcn_mfma_f32_16x16x32_bf16(af[m], bfr[n], acc[m][n], 0, 0, 0);
    }
    __syncthreads();
  }

  const int r0 = bm * 128 + wr * 64;
  const int c0 = bn * 128 + wc * 64;
#pragma unroll
  for (int n = 0; n < 4; ++n) {
    int col = c0 + n * 16 + frow;
    float bv = bias[col];
#pragma unroll
    for (int m = 0; m < 4; ++m)
#pragma unroll
      for (int j = 0; j < 4; ++j) {
        int row = r0 + m * 16 + kgrp * 4 + j;
        out[(size_t)row * H_DIM + col] = __float2bfloat16(fmaxf(acc[m][n][j] + bv, 0.f));
      }
  }
}

// ---------------- 256-row-tile core for bicep/final (R8/R9 proven) -------------
// BM=256, BN=128, BK=64, 8 waves, counted-vmcnt dbuf + pre-swizzled-source T2
// + XCD-aware bijective tile remap. MODE 2: +bias+extra->bf16 ; MODE 3: fp32.
template <int MODE>
__global__ __launch_bounds__(512) void gemm8(
    const __hip_bfloat16* __restrict__ A, const __hip_bfloat16* __restrict__ Bt,
    const float* __restrict__ bias, const __hip_bfloat16* __restrict__ extra,
    void* __restrict__ out, int N, int K, int nGemm) {
  constexpr int SMHALF = (256 + 128) * 64 * 2;
  __shared__ char smem[2 * SMHALF];

  const int tid = threadIdx.x;
  const int lane = tid & 63, wid = tid >> 6;
  const int wm = wid >> 2, wn = wid & 3;
  const int frow = lane & 15, kgrp = lane >> 4;
  const int cpx = nGemm >> 3;
  const int gb = (blockIdx.x & 7) * cpx + (blockIdx.x >> 3);  // XCD remap
  const int gx = N / 128;
  const int bm = gb / gx, bn = gb % gx;
  const size_t arow0 = (size_t)(bm * 256) * K;
  const size_t brow0 = (size_t)(bn * 128) * K;

  auto stage = [&](int kt, int d) {
    char* dst = smem + d * SMHALF;
#pragma unroll
    for (int j = 0; j < 6; ++j) {
      int c = j * 512 + tid;
      if (j < 4) {  // A tile: 256x64
        int row = c >> 3, cb = (c & 7) * 16;
        int col = (cb ^ ((row & 7) << 4)) >> 1;
        gld_lds16((const void*)(A + arow0 + (size_t)row * K + kt + col), dst + c * 16);
      } else {      // B tile: 128x64
        int cB = c - 2048;
        int row = cB >> 3, cb = (cB & 7) * 16;
        int col = (cb ^ ((row & 7) << 4)) >> 1;
        gld_lds16((const void*)(Bt + brow0 + (size_t)row * K + kt + col), dst + 32768 + cB * 16);
      }
    }
  };

  f32x4 acc[8][2];
#pragma unroll
  for (int m = 0; m < 8; ++m)
#pragma unroll
    for (int n = 0; n < 2; ++n) acc[m][n] = (f32x4){0.f, 0.f, 0.f, 0.f};

  stage(0, 0);
  const int NT = K >> 6;
  for (int t = 0; t < NT; ++t) {
    const int cur = t & 1;
    if (t + 1 < NT) stage((t + 1) << 6, cur ^ 1);
    if (t == 0 || t + 1 >= NT) {
      asm volatile("s_waitcnt vmcnt(0)" ::: "memory");
    } else {
      asm volatile("s_waitcnt vmcnt(6)" ::: "memory");
    }
    __builtin_amdgcn_s_barrier();

    const char* Ab = smem + cur * SMHALF;
    const char* Bb = Ab + 32768;
    bf16x8 bfr[2][2];
#pragma unroll
    for (int n = 0; n < 2; ++n)
#pragma unroll
      for (int s = 0; s < 2; ++s) {
        int row = wn * 32 + n * 16 + frow;
        int cb = s * 64 + kgrp * 16;
        bfr[n][s] = *(const bf16x8*)(Bb + row * 128 + (cb ^ ((row & 7) << 4)));
      }
#pragma unroll
    for (int mh = 0; mh < 2; ++mh) {
      bf16x8 af[4][2];
#pragma unroll
      for (int m = 0; m < 4; ++m)
#pragma unroll
        for (int s = 0; s < 2; ++s) {
          int row = wm * 128 + (mh * 4 + m) * 16 + frow;
          int cb = s * 64 + kgrp * 16;
          af[m][s] = *(const bf16x8*)(Ab + row * 128 + (cb ^ ((row & 7) << 4)));
        }
#pragma unroll
      for (int m = 0; m < 4; ++m)
#pragma unroll
        for (int n = 0; n < 2; ++n)
#pragma unroll
          for (int s = 0; s < 2; ++s)
            acc[mh * 4 + m][n] = __builtin_amdgcn_mfma_f32_16x16x32_bf16(
                af[m][s], bfr[n][s], acc[mh * 4 + m][n], 0, 0, 0);
    }
    __builtin_amdgcn_s_barrier();
  }

  const int r0 = bm * 256 + wm * 128;
  const int c0 = bn * 128 + wn * 32;
#pragma unroll
  for (int n = 0; n < 2; ++n) {
    int col = c0 + n * 16 + frow;
    float bv = bias[col];
#pragma unroll
    for (int m = 0; m < 8; ++m)
#pragma unroll
      for (int j = 0; j < 4; ++j) {
        int row = r0 + m * 16 + kgrp * 4 + j;
        float v = acc[m][n][j] + bv;
        if (MODE == 2) {
          v += __bfloat162float(extra[(size_t)row * N + col]);
          ((__hip_bfloat16*)out)[(size_t)row * N + col] = __float2bfloat16(v);
        } else {
          ((float*)out)[(size_t)row * N + col] = v;
        }
      }
  }
}

extern "C" void kernel_launch(void* const* d_in, const int* in_sizes, int n_in,
                              void* d_out, int out_size, void* d_ws, size_t ws_size,
                              hipStream_t stream) {
  (void)in_sizes; (void)n_in; (void)out_size; (void)ws_size;
  const float* x     = (const float*)d_in[0];
  const float* W_in  = (const float*)d_in[1];
  const float* b_in  = (const float*)d_in[2];
  const float* W_hid = (const float*)d_in[3];
  const float* b_hid = (const float*)d_in[4];
  const float* W_fb  = (const float*)d_in[5];
  const float* b_fb  = (const float*)d_in[6];
  const float* W_agg = (const float*)d_in[7];
  const float* b_agg = (const float*)d_in[8];
  const float* W_out = (const float*)d_in[9];
  const float* b_out = (const float*)d_in[10];
  const float* noise = (const float*)d_in[11];

  const int B = B_DIM, H = H_DIM, P = NPATH;
  const int R = B * P;

  size_t off = 0;
  char* base = (char*)d_ws;
  auto take = [&](size_t bytes) -> char* {
    char* r = base + off;
    off = (off + bytes + 255) & ~(size_t)255;
    return r;
  };
  __hip_bfloat16* xb    = (__hip_bfloat16*)take((size_t)B * H * 2);  // reused as `combined`
  __hip_bfloat16* h1b   = (__hip_bfloat16*)take((size_t)B * H * 2);
  __hip_bfloat16* h2b   = (__hip_bfloat16*)take((size_t)B * H * 2);
  __hip_bfloat16* wtin  = (__hip_bfloat16*)take((size_t)H * H * 2);
  __hip_bfloat16* wthid = (__hip_bfloat16*)take((size_t)H * H * 2);
  __hip_bfloat16* wtout = (__hip_bfloat16*)take((size_t)H * H * 2);
  __hip_bfloat16* wtagg = (__hip_bfloat16*)take((size_t)H * P * 2);
  float* ns = (float*)take((size_t)R * 4);
  __hip_bfloat16* eb = (__hip_bfloat16*)take((size_t)R * 2);

  float dt = 1.0f / NSTEP;
  float DI = 0.f;
  for (int j = 0; j < NSTEP; ++j) DI += expf(-0.1f * ((float)j * dt));
  DI *= dt;
  float SQDT = sqrtf(dt);

  prep_kernel<<<11520, 256, 0, stream>>>(x, W_in, W_hid, W_out, W_agg,
                                         xb, wtin, wthid, wtout, wtagg);

  // trunk stages: 512 blocks, each = 4 GEMM waves + 1 noise wave (2048 rows)
  stage_kernel<<<512, 320, 0, stream>>>(xb, wtin, b_in, h1b, noise, ns, 0);
  stage_kernel<<<512, 320, 0, stream>>>(h1b, wthid, b_hid, h2b, noise, ns, R / 2);
  fb_end_kernel<<<B / 4, 256, 0, stream>>>(h2b, W_fb, b_fb, ns, eb, DI, SQDT);
  // bicep: eb @ wtagg^T + b_agg + h2 -> xb (combined), K=256
  gemm8<2><<<256, 512, 0, stream>>>(eb, wtagg, b_agg, h2b, xb, H, P, 256);
  // final: combined @ W_out^T + b_out -> fp32 d_out, K=1024
  gemm8<3><<<256, 512, 0, stream>>>(xb, wtout, b_out, nullptr, d_out, H, H, 256);
}

// Round 13
// 302.762 us; speedup vs baseline: 1.5693x; 1.5693x over previous
//
#include <hip/hip_runtime.h>
#include <hip/hip_bf16.h>
#include <math.h>

typedef short bf16x8 __attribute__((ext_vector_type(8)));
typedef float f32x4 __attribute__((ext_vector_type(4)));
typedef unsigned int u32;

#define B_DIM 8192
#define H_DIM 1024
#define NPATH 256
#define NSTEP 50

__device__ __forceinline__ void gld_lds16(const void* g, void* lds) {
  __builtin_amdgcn_global_load_lds(
      (const __attribute__((address_space(1))) u32*)g,
      (__attribute__((address_space(3))) u32*)lds, 16, 0, 0);
}

__device__ __forceinline__ void cast4(const float* in, __hip_bfloat16* out, int i) {
  float4 v = ((const float4*)in)[i];
  union { __hip_bfloat16 h[4]; short4 s; } u;
  u.h[0] = __float2bfloat16(v.x);
  u.h[1] = __float2bfloat16(v.y);
  u.h[2] = __float2bfloat16(v.z);
  u.h[3] = __float2bfloat16(v.w);
  ((short4*)out)[i] = u.s;
}

// ---------------- fused prep: pure data movement ----------------
// [0,8192) cast x ; [8192,11264) transpose W_in/W_hid/W_out ; [11264,11520) W_agg^T
__global__ __launch_bounds__(256) void prep_kernel(
    const float* __restrict__ x, const float* __restrict__ W_in,
    const float* __restrict__ W_hid, const float* __restrict__ W_out,
    const float* __restrict__ W_agg,
    __hip_bfloat16* __restrict__ xb, __hip_bfloat16* __restrict__ wtin,
    __hip_bfloat16* __restrict__ wthid, __hip_bfloat16* __restrict__ wtout,
    __hip_bfloat16* __restrict__ wtagg) {
  __shared__ float t[32][33];
  int bid = blockIdx.x, tid = threadIdx.x;
  if (bid < 8192) {
    cast4(x, xb, bid * 256 + tid);
    return;
  }
  int job = bid - 8192;
  const float* W; __hip_bfloat16* Wt; int R, C;
  if (job < 1024)      { W = W_in;  Wt = wtin;  R = 1024; C = 1024; }
  else if (job < 2048) { W = W_hid; Wt = wthid; R = 1024; C = 1024; job -= 1024; }
  else if (job < 3072) { W = W_out; Wt = wtout; R = 1024; C = 1024; job -= 2048; }
  else                 { W = W_agg; Wt = wtagg; R = 256;  C = 1024; job -= 3072; }
  int nTx = C / 32;
  int tX = job % nTx, tY = job / nTx;
  int tx = tid & 31, r4 = tid >> 5;
#pragma unroll
  for (int i = 0; i < 4; ++i) {
    int ty = r4 * 4 + i;
    t[ty][tx] = W[(size_t)(tY * 32 + ty) * C + tX * 32 + tx];
  }
  __syncthreads();
#pragma unroll
  for (int i = 0; i < 4; ++i) {
    int ty = r4 * 4 + i;
    Wt[(size_t)(tX * 32 + ty) * R + tY * 32 + tx] = __float2bfloat16(t[tx][ty]);
  }
}

// ------------- fused feedback + endpoints: per block = 4 batch rows -------------
__global__ __launch_bounds__(256) void fb_end_kernel(
    const __hip_bfloat16* __restrict__ h2b, const float* __restrict__ Wfb,
    const float* __restrict__ bfb, const float* __restrict__ ns,
    __hip_bfloat16* __restrict__ eb, float DI, float SQDT) {
  __shared__ float fv[4];
  int wid = threadIdx.x >> 6, lane = threadIdx.x & 63;
  int row = blockIdx.x * 4 + wid;
  const __hip_bfloat16* hrow = h2b + (size_t)row * H_DIM;
  float s = 0.f;
#pragma unroll
  for (int i = lane; i < H_DIM; i += 64) s += __bfloat162float(hrow[i]) * Wfb[i];
#pragma unroll
  for (int off = 32; off > 0; off >>= 1) s += __shfl_down(s, off);
  if (lane == 0) fv[wid] = 1.0f / (1.0f + expf(-(s + bfb[0])));
  __syncthreads();
#pragma unroll
  for (int w = 0; w < 4; ++w) {
    size_t i = (size_t)(blockIdx.x * 4 + w) * NPATH + threadIdx.x;
    eb[i] = __float2bfloat16(fv[w] * DI + SQDT * ns[i]);
  }
}

// -------- trunk stage: SAME-WAVE fused GEMM + noise (no cross-wave coupling) ----
// 512 blocks x 256 threads, 128x128 MFMA tile, 32KB LDS (4-5 blocks/CU).
// Each block also owns 2048 noise rows; per K-iteration each THREAD-PAIR reduces
// one row (lane0: 12 float2, lane1: 13 float2, shfl_xor combine) — the loads are
// issued by the same waves that run MFMA, so latency hides under the MFMA phase
// and co-resident blocks. No wave ever waits on another wave's memory (R12's
// failure), and no dependence on block->XCD placement (R9/R10's failure).
__global__ __launch_bounds__(256) void stage_kernel(
    const __hip_bfloat16* __restrict__ A, const __hip_bfloat16* __restrict__ Bt,
    const float* __restrict__ bias, __hip_bfloat16* __restrict__ out,
    const float* __restrict__ noise, float* __restrict__ ns, int rowStart) {
  __shared__ __hip_bfloat16 As[128 * 64];
  __shared__ __hip_bfloat16 Bs[128 * 64];
  const int tid = threadIdx.x;
  const int gb = blockIdx.x;               // 512 tiles, bm-major
  const int bm = gb >> 3, bn = gb & 7;
  const int lane = tid & 63, wid = tid >> 6;
  const int wr = wid >> 1, wc = wid & 1;
  const int frow = lane & 15, kgrp = lane >> 4;

  // noise ownership: 2048 rows/block, 128 rows per K-iter, pair = tid>>1
  const int half = tid & 1;
  const int rb = rowStart + gb * 2048 + (tid >> 1);
  const int j0 = half * 12, j1 = half ? 25 : 12;

  f32x4 acc[4][4];
#pragma unroll
  for (int m = 0; m < 4; ++m)
#pragma unroll
    for (int n = 0; n < 4; ++n) acc[m][n] = (f32x4){0.f, 0.f, 0.f, 0.f};

  for (int it = 0; it < 16; ++it) {
    const int kt = it * 64;
#pragma unroll
    for (int r = 0; r < 4; ++r) {
      int c = r * 256 + tid;
      int row = c >> 3, cc = c & 7;
      gld_lds16((const char*)(A + (size_t)(bm * 128 + row) * H_DIM + kt) + cc * 16,
                (char*)As + c * 16);
      gld_lds16((const char*)(Bt + (size_t)(bn * 128 + row) * H_DIM + kt) + cc * 16,
                (char*)Bs + c * 16);
    }
    // fused noise chunk: issued by the same wave, latency hidden by MFMA below
    {
      int row = rb + it * 128;
      const float2* p = (const float2*)(noise + (size_t)row * NSTEP);
      float s = 0.f;
#pragma unroll
      for (int j = j0; j < j1; ++j) { float2 v = p[j]; s += v.x + v.y; }
      s += __shfl_xor(s, 1);
      if (!half) ns[row] = s;
    }
    __syncthreads();
#pragma unroll
    for (int kk = 0; kk < 64; kk += 32) {
      bf16x8 af[4], bfr[4];
#pragma unroll
      for (int m = 0; m < 4; ++m)
        af[m] = *(const bf16x8*)(As + (wr * 64 + m * 16 + frow) * 64 + kk + kgrp * 8);
#pragma unroll
      for (int n = 0; n < 4; ++n)
        bfr[n] = *(const bf16x8*)(Bs + (wc * 64 + n * 16 + frow) * 64 + kk + kgrp * 8);
#pragma unroll
      for (int m = 0; m < 4; ++m)
#pragma unroll
        for (int n = 0; n < 4; ++n)
          acc[m][n] = __builtin_amdgcn_mfma_f32_16x16x32_bf16(af[m], bfr[n], acc[m][n], 0, 0, 0);
    }
    __syncthreads();
  }

  const int r0 = bm * 128 + wr * 64;
  const int c0 = bn * 128 + wc * 64;
#pragma unroll
  for (int n = 0; n < 4; ++n) {
    int col = c0 + n * 16 + frow;
    float bv = bias[col];
#pragma unroll
    for (int m = 0; m < 4; ++m)
#pragma unroll
      for (int j = 0; j < 4; ++j) {
        int row = r0 + m * 16 + kgrp * 4 + j;
        out[(size_t)row * H_DIM + col] = __float2bfloat16(fmaxf(acc[m][n][j] + bv, 0.f));
      }
  }
}

// ---------------- 256-row-tile core for bicep/final (R8/R9 proven) -------------
// BM=256, BN=128, BK=64, 8 waves, counted-vmcnt dbuf + pre-swizzled-source T2
// + XCD-aware bijective tile remap. MODE 2: +bias+extra->bf16 ; MODE 3: fp32.
template <int MODE>
__global__ __launch_bounds__(512) void gemm8(
    const __hip_bfloat16* __restrict__ A, const __hip_bfloat16* __restrict__ Bt,
    const float* __restrict__ bias, const __hip_bfloat16* __restrict__ extra,
    void* __restrict__ out, int N, int K, int nGemm) {
  constexpr int SMHALF = (256 + 128) * 64 * 2;
  __shared__ char smem[2 * SMHALF];

  const int tid = threadIdx.x;
  const int lane = tid & 63, wid = tid >> 6;
  const int wm = wid >> 2, wn = wid & 3;
  const int frow = lane & 15, kgrp = lane >> 4;
  const int cpx = nGemm >> 3;
  const int gb = (blockIdx.x & 7) * cpx + (blockIdx.x >> 3);  // XCD remap
  const int gx = N / 128;
  const int bm = gb / gx, bn = gb % gx;
  const size_t arow0 = (size_t)(bm * 256) * K;
  const size_t brow0 = (size_t)(bn * 128) * K;

  auto stage = [&](int kt, int d) {
    char* dst = smem + d * SMHALF;
#pragma unroll
    for (int j = 0; j < 6; ++j) {
      int c = j * 512 + tid;
      if (j < 4) {  // A tile: 256x64
        int row = c >> 3, cb = (c & 7) * 16;
        int col = (cb ^ ((row & 7) << 4)) >> 1;
        gld_lds16((const void*)(A + arow0 + (size_t)row * K + kt + col), dst + c * 16);
      } else {      // B tile: 128x64
        int cB = c - 2048;
        int row = cB >> 3, cb = (cB & 7) * 16;
        int col = (cb ^ ((row & 7) << 4)) >> 1;
        gld_lds16((const void*)(Bt + brow0 + (size_t)row * K + kt + col), dst + 32768 + cB * 16);
      }
    }
  };

  f32x4 acc[8][2];
#pragma unroll
  for (int m = 0; m < 8; ++m)
#pragma unroll
    for (int n = 0; n < 2; ++n) acc[m][n] = (f32x4){0.f, 0.f, 0.f, 0.f};

  stage(0, 0);
  const int NT = K >> 6;
  for (int t = 0; t < NT; ++t) {
    const int cur = t & 1;
    if (t + 1 < NT) stage((t + 1) << 6, cur ^ 1);
    if (t == 0 || t + 1 >= NT) {
      asm volatile("s_waitcnt vmcnt(0)" ::: "memory");
    } else {
      asm volatile("s_waitcnt vmcnt(6)" ::: "memory");
    }
    __builtin_amdgcn_s_barrier();

    const char* Ab = smem + cur * SMHALF;
    const char* Bb = Ab + 32768;
    bf16x8 bfr[2][2];
#pragma unroll
    for (int n = 0; n < 2; ++n)
#pragma unroll
      for (int s = 0; s < 2; ++s) {
        int row = wn * 32 + n * 16 + frow;
        int cb = s * 64 + kgrp * 16;
        bfr[n][s] = *(const bf16x8*)(Bb + row * 128 + (cb ^ ((row & 7) << 4)));
      }
#pragma unroll
    for (int mh = 0; mh < 2; ++mh) {
      bf16x8 af[4][2];
#pragma unroll
      for (int m = 0; m < 4; ++m)
#pragma unroll
        for (int s = 0; s < 2; ++s) {
          int row = wm * 128 + (mh * 4 + m) * 16 + frow;
          int cb = s * 64 + kgrp * 16;
          af[m][s] = *(const bf16x8*)(Ab + row * 128 + (cb ^ ((row & 7) << 4)));
        }
#pragma unroll
      for (int m = 0; m < 4; ++m)
#pragma unroll
        for (int n = 0; n < 2; ++n)
#pragma unroll
          for (int s = 0; s < 2; ++s)
            acc[mh * 4 + m][n] = __builtin_amdgcn_mfma_f32_16x16x32_bf16(
                af[m][s], bfr[n][s], acc[mh * 4 + m][n], 0, 0, 0);
    }
    __builtin_amdgcn_s_barrier();
  }

  const int r0 = bm * 256 + wm * 128;
  const int c0 = bn * 128 + wn * 32;
#pragma unroll
  for (int n = 0; n < 2; ++n) {
    int col = c0 + n * 16 + frow;
    float bv = bias[col];
#pragma unroll
    for (int m = 0; m < 8; ++m)
#pragma unroll
      for (int j = 0; j < 4; ++j) {
        int row = r0 + m * 16 + kgrp * 4 + j;
        float v = acc[m][n][j] + bv;
        if (MODE == 2) {
          v += __bfloat162float(extra[(size_t)row * N + col]);
          ((__hip_bfloat16*)out)[(size_t)row * N + col] = __float2bfloat16(v);
        } else {
          ((float*)out)[(size_t)row * N + col] = v;
        }
      }
  }
}

extern "C" void kernel_launch(void* const* d_in, const int* in_sizes, int n_in,
                              void* d_out, int out_size, void* d_ws, size_t ws_size,
                              hipStream_t stream) {
  (void)in_sizes; (void)n_in; (void)out_size; (void)ws_size;
  const float* x     = (const float*)d_in[0];
  const float* W_in  = (const float*)d_in[1];
  const float* b_in  = (const float*)d_in[2];
  const float* W_hid = (const float*)d_in[3];
  const float* b_hid = (const float*)d_in[4];
  const float* W_fb  = (const float*)d_in[5];
  const float* b_fb  = (const float*)d_in[6];
  const float* W_agg = (const float*)d_in[7];
  const float* b_agg = (const float*)d_in[8];
  const float* W_out = (const float*)d_in[9];
  const float* b_out = (const float*)d_in[10];
  const float* noise = (const float*)d_in[11];

  const int B = B_DIM, H = H_DIM, P = NPATH;
  const int R = B * P;

  size_t off = 0;
  char* base = (char*)d_ws;
  auto take = [&](size_t bytes) -> char* {
    char* r = base + off;
    off = (off + bytes + 255) & ~(size_t)255;
    return r;
  };
  __hip_bfloat16* xb    = (__hip_bfloat16*)take((size_t)B * H * 2);  // reused as `combined`
  __hip_bfloat16* h1b   = (__hip_bfloat16*)take((size_t)B * H * 2);
  __hip_bfloat16* h2b   = (__hip_bfloat16*)take((size_t)B * H * 2);
  __hip_bfloat16* wtin  = (__hip_bfloat16*)take((size_t)H * H * 2);
  __hip_bfloat16* wthid = (__hip_bfloat16*)take((size_t)H * H * 2);
  __hip_bfloat16* wtout = (__hip_bfloat16*)take((size_t)H * H * 2);
  __hip_bfloat16* wtagg = (__hip_bfloat16*)take((size_t)H * P * 2);
  float* ns = (float*)take((size_t)R * 4);
  __hip_bfloat16* eb = (__hip_bfloat16*)take((size_t)R * 2);

  float dt = 1.0f / NSTEP;
  float DI = 0.f;
  for (int j = 0; j < NSTEP; ++j) DI += expf(-0.1f * ((float)j * dt));
  DI *= dt;
  float SQDT = sqrtf(dt);

  prep_kernel<<<11520, 256, 0, stream>>>(x, W_in, W_hid, W_out, W_agg,
                                         xb, wtin, wthid, wtout, wtagg);

  // trunk stages: 512 blocks, GEMM tile + 2048 noise rows fused into same waves
  stage_kernel<<<512, 256, 0, stream>>>(xb, wtin, b_in, h1b, noise, ns, 0);
  stage_kernel<<<512, 256, 0, stream>>>(h1b, wthid, b_hid, h2b, noise, ns, R / 2);
  fb_end_kernel<<<B / 4, 256, 0, stream>>>(h2b, W_fb, b_fb, ns, eb, DI, SQDT);
  // bicep: eb @ wtagg^T + b_agg + h2 -> xb (combined), K=256
  gemm8<2><<<256, 512, 0, stream>>>(eb, wtagg, b_agg, h2b, xb, H, P, 256);
  // final: combined @ W_out^T + b_out -> fp32 d_out, K=1024
  gemm8<3><<<256, 512, 0, stream>>>(xb, wtout, b_out, nullptr, d_out, H, H, 256);
}

// Round 14
// 200.030 us; speedup vs baseline: 2.3753x; 1.5136x over previous
//
#include <hip/hip_runtime.h>
#include <hip/hip_bf16.h>
#include <math.h>

typedef short bf16x8 __attribute__((ext_vector_type(8)));
typedef float f32x4 __attribute__((ext_vector_type(4)));
typedef unsigned int u32;

#define B_DIM 8192
#define H_DIM 1024
#define NPATH 256
#define NSTEP 50

__device__ __forceinline__ void gld_lds16(const void* g, void* lds) {
  __builtin_amdgcn_global_load_lds(
      (const __attribute__((address_space(1))) u32*)g,
      (__attribute__((address_space(3))) u32*)lds, 16, 0, 0);
}

__device__ __forceinline__ void cast4(const float* in, __hip_bfloat16* out, int i) {
  float4 v = ((const float4*)in)[i];
  union { __hip_bfloat16 h[4]; short4 s; } u;
  u.h[0] = __float2bfloat16(v.x);
  u.h[1] = __float2bfloat16(v.y);
  u.h[2] = __float2bfloat16(v.z);
  u.h[3] = __float2bfloat16(v.w);
  ((short4*)out)[i] = u.s;
}

// ---------- fused prep + noise: ONE uniform streaming kernel (full-chip BW) ----
// Co-scheduling noise with GEMMs failed 4 ways (R9/R10/R12/R13): block splits
// partition CUs, wave/thread fusion couples noise latency into the barrier's
// vmcnt(0) drain. Serial streaming at full chip is the true floor (~58us for
// 400MB noise + 68MB prep).
// [0,8192)        cast x -> xb
// [8192,11264)    transpose+cast W_in/W_hid/W_out (1024 32x32 tiles each)
// [11264,11520)   transpose+cast W_agg
// [11520,19712)   noise row-sums: 8192 blocks x 256 rows (1 thread/row, float2)
__global__ __launch_bounds__(256) void prep_kernel(
    const float* __restrict__ x, const float* __restrict__ W_in,
    const float* __restrict__ W_hid, const float* __restrict__ W_out,
    const float* __restrict__ W_agg, const float* __restrict__ noise,
    __hip_bfloat16* __restrict__ xb, __hip_bfloat16* __restrict__ wtin,
    __hip_bfloat16* __restrict__ wthid, __hip_bfloat16* __restrict__ wtout,
    __hip_bfloat16* __restrict__ wtagg, float* __restrict__ ns) {
  __shared__ float t[32][33];
  int bid = blockIdx.x, tid = threadIdx.x;
  if (bid < 8192) {
    cast4(x, xb, bid * 256 + tid);
    return;
  }
  if (bid >= 11520) {
    int row = (bid - 11520) * 256 + tid;
    const float2* p = (const float2*)(noise + (size_t)row * NSTEP);
    float s = 0.f;
#pragma unroll
    for (int i = 0; i < NSTEP / 2; ++i) { float2 v = p[i]; s += v.x + v.y; }
    ns[row] = s;
    return;
  }
  int job = bid - 8192;
  const float* W; __hip_bfloat16* Wt; int R, C;
  if (job < 1024)      { W = W_in;  Wt = wtin;  R = 1024; C = 1024; }
  else if (job < 2048) { W = W_hid; Wt = wthid; R = 1024; C = 1024; job -= 1024; }
  else if (job < 3072) { W = W_out; Wt = wtout; R = 1024; C = 1024; job -= 2048; }
  else                 { W = W_agg; Wt = wtagg; R = 256;  C = 1024; job -= 3072; }
  int nTx = C / 32;
  int tX = job % nTx, tY = job / nTx;
  int tx = tid & 31, r4 = tid >> 5;
#pragma unroll
  for (int i = 0; i < 4; ++i) {
    int ty = r4 * 4 + i;
    t[ty][tx] = W[(size_t)(tY * 32 + ty) * C + tX * 32 + tx];
  }
  __syncthreads();
#pragma unroll
  for (int i = 0; i < 4; ++i) {
    int ty = r4 * 4 + i;
    Wt[(size_t)(tX * 32 + ty) * R + tY * 32 + tx] = __float2bfloat16(t[tx][ty]);
  }
}

// ------------- fused feedback + endpoints: per block = 4 batch rows -------------
__global__ __launch_bounds__(256) void fb_end_kernel(
    const __hip_bfloat16* __restrict__ h2b, const float* __restrict__ Wfb,
    const float* __restrict__ bfb, const float* __restrict__ ns,
    __hip_bfloat16* __restrict__ eb, float DI, float SQDT) {
  __shared__ float fv[4];
  int wid = threadIdx.x >> 6, lane = threadIdx.x & 63;
  int row = blockIdx.x * 4 + wid;
  const __hip_bfloat16* hrow = h2b + (size_t)row * H_DIM;
  float s = 0.f;
#pragma unroll
  for (int i = lane; i < H_DIM; i += 64) s += __bfloat162float(hrow[i]) * Wfb[i];
#pragma unroll
  for (int off = 32; off > 0; off >>= 1) s += __shfl_down(s, off);
  if (lane == 0) fv[wid] = 1.0f / (1.0f + expf(-(s + bfb[0])));
  __syncthreads();
#pragma unroll
  for (int w = 0; w < 4; ++w) {
    size_t i = (size_t)(blockIdx.x * 4 + w) * NPATH + threadIdx.x;
    eb[i] = __float2bfloat16(fv[w] * DI + SQDT * ns[i]);
  }
}

// ---------------- 256x128-tile GEMM core, full-chip (256 blocks = 1/CU) --------
// BM=256, BN=128, BK=64, 8 waves, counted-vmcnt dbuf + pre-swizzled-source T2
// + XCD-aware bijective tile remap.
// MODE 0: relu(acc+bias)->bf16 ; MODE 2: acc+bias+extra->bf16 ; MODE 3: fp32.
template <int MODE>
__global__ __launch_bounds__(512) void gemm8(
    const __hip_bfloat16* __restrict__ A, const __hip_bfloat16* __restrict__ Bt,
    const float* __restrict__ bias, const __hip_bfloat16* __restrict__ extra,
    void* __restrict__ out, int N, int K, int nGemm) {
  constexpr int SMHALF = (256 + 128) * 64 * 2;
  __shared__ char smem[2 * SMHALF];

  const int tid = threadIdx.x;
  const int lane = tid & 63, wid = tid >> 6;
  const int wm = wid >> 2, wn = wid & 3;
  const int frow = lane & 15, kgrp = lane >> 4;
  const int cpx = nGemm >> 3;
  const int gb = (blockIdx.x & 7) * cpx + (blockIdx.x >> 3);  // XCD remap
  const int gx = N / 128;
  const int bm = gb / gx, bn = gb % gx;
  const size_t arow0 = (size_t)(bm * 256) * K;
  const size_t brow0 = (size_t)(bn * 128) * K;

  auto stage = [&](int kt, int d) {
    char* dst = smem + d * SMHALF;
#pragma unroll
    for (int j = 0; j < 6; ++j) {
      int c = j * 512 + tid;
      if (j < 4) {  // A tile: 256x64
        int row = c >> 3, cb = (c & 7) * 16;
        int col = (cb ^ ((row & 7) << 4)) >> 1;
        gld_lds16((const void*)(A + arow0 + (size_t)row * K + kt + col), dst + c * 16);
      } else {      // B tile: 128x64
        int cB = c - 2048;
        int row = cB >> 3, cb = (cB & 7) * 16;
        int col = (cb ^ ((row & 7) << 4)) >> 1;
        gld_lds16((const void*)(Bt + brow0 + (size_t)row * K + kt + col), dst + 32768 + cB * 16);
      }
    }
  };

  f32x4 acc[8][2];
#pragma unroll
  for (int m = 0; m < 8; ++m)
#pragma unroll
    for (int n = 0; n < 2; ++n) acc[m][n] = (f32x4){0.f, 0.f, 0.f, 0.f};

  stage(0, 0);
  const int NT = K >> 6;
  for (int t = 0; t < NT; ++t) {
    const int cur = t & 1;
    if (t + 1 < NT) stage((t + 1) << 6, cur ^ 1);
    if (t == 0 || t + 1 >= NT) {
      asm volatile("s_waitcnt vmcnt(0)" ::: "memory");
    } else {
      asm volatile("s_waitcnt vmcnt(6)" ::: "memory");
    }
    __builtin_amdgcn_s_barrier();

    const char* Ab = smem + cur * SMHALF;
    const char* Bb = Ab + 32768;
    bf16x8 bfr[2][2];
#pragma unroll
    for (int n = 0; n < 2; ++n)
#pragma unroll
      for (int s = 0; s < 2; ++s) {
        int row = wn * 32 + n * 16 + frow;
        int cb = s * 64 + kgrp * 16;
        bfr[n][s] = *(const bf16x8*)(Bb + row * 128 + (cb ^ ((row & 7) << 4)));
      }
#pragma unroll
    for (int mh = 0; mh < 2; ++mh) {
      bf16x8 af[4][2];
#pragma unroll
      for (int m = 0; m < 4; ++m)
#pragma unroll
        for (int s = 0; s < 2; ++s) {
          int row = wm * 128 + (mh * 4 + m) * 16 + frow;
          int cb = s * 64 + kgrp * 16;
          af[m][s] = *(const bf16x8*)(Ab + row * 128 + (cb ^ ((row & 7) << 4)));
        }
#pragma unroll
      for (int m = 0; m < 4; ++m)
#pragma unroll
        for (int n = 0; n < 2; ++n)
#pragma unroll
          for (int s = 0; s < 2; ++s)
            acc[mh * 4 + m][n] = __builtin_amdgcn_mfma_f32_16x16x32_bf16(
                af[m][s], bfr[n][s], acc[mh * 4 + m][n], 0, 0, 0);
    }
    __builtin_amdgcn_s_barrier();
  }

  const int r0 = bm * 256 + wm * 128;
  const int c0 = bn * 128 + wn * 32;
#pragma unroll
  for (int n = 0; n < 2; ++n) {
    int col = c0 + n * 16 + frow;
    float bv = bias[col];
#pragma unroll
    for (int m = 0; m < 8; ++m)
#pragma unroll
      for (int j = 0; j < 4; ++j) {
        int row = r0 + m * 16 + kgrp * 4 + j;
        float v = acc[m][n][j] + bv;
        if (MODE == 0) {
          v = fmaxf(v, 0.f);
          ((__hip_bfloat16*)out)[(size_t)row * N + col] = __float2bfloat16(v);
        } else if (MODE == 2) {
          v += __bfloat162float(extra[(size_t)row * N + col]);
          ((__hip_bfloat16*)out)[(size_t)row * N + col] = __float2bfloat16(v);
        } else {
          ((float*)out)[(size_t)row * N + col] = v;
        }
      }
  }
}

extern "C" void kernel_launch(void* const* d_in, const int* in_sizes, int n_in,
                              void* d_out, int out_size, void* d_ws, size_t ws_size,
                              hipStream_t stream) {
  (void)in_sizes; (void)n_in; (void)out_size; (void)ws_size;
  const float* x     = (const float*)d_in[0];
  const float* W_in  = (const float*)d_in[1];
  const float* b_in  = (const float*)d_in[2];
  const float* W_hid = (const float*)d_in[3];
  const float* b_hid = (const float*)d_in[4];
  const float* W_fb  = (const float*)d_in[5];
  const float* b_fb  = (const float*)d_in[6];
  const float* W_agg = (const float*)d_in[7];
  const float* b_agg = (const float*)d_in[8];
  const float* W_out = (const float*)d_in[9];
  const float* b_out = (const float*)d_in[10];
  const float* noise = (const float*)d_in[11];

  const int B = B_DIM, H = H_DIM, P = NPATH;
  const int R = B * P;

  size_t off = 0;
  char* base = (char*)d_ws;
  auto take = [&](size_t bytes) -> char* {
    char* r = base + off;
    off = (off + bytes + 255) & ~(size_t)255;
    return r;
  };
  __hip_bfloat16* xb    = (__hip_bfloat16*)take((size_t)B * H * 2);  // reused as `combined`
  __hip_bfloat16* h1b   = (__hip_bfloat16*)take((size_t)B * H * 2);
  __hip_bfloat16* h2b   = (__hip_bfloat16*)take((size_t)B * H * 2);
  __hip_bfloat16* wtin  = (__hip_bfloat16*)take((size_t)H * H * 2);
  __hip_bfloat16* wthid = (__hip_bfloat16*)take((size_t)H * H * 2);
  __hip_bfloat16* wtout = (__hip_bfloat16*)take((size_t)H * H * 2);
  __hip_bfloat16* wtagg = (__hip_bfloat16*)take((size_t)H * P * 2);
  float* ns = (float*)take((size_t)R * 4);
  __hip_bfloat16* eb = (__hip_bfloat16*)take((size_t)R * 2);

  float dt = 1.0f / NSTEP;
  float DI = 0.f;
  for (int j = 0; j < NSTEP; ++j) DI += expf(-0.1f * ((float)j * dt));
  DI *= dt;
  float SQDT = sqrtf(dt);

  // prep + noise: one uniform full-chip streaming kernel (~468 MB)
  prep_kernel<<<19712, 256, 0, stream>>>(x, W_in, W_hid, W_out, W_agg, noise,
                                         xb, wtin, wthid, wtout, wtagg, ns);
  // trunk GEMMs: full chip, 256 blocks each
  gemm8<0><<<256, 512, 0, stream>>>(xb, wtin, b_in, nullptr, h1b, H, H, 256);
  gemm8<0><<<256, 512, 0, stream>>>(h1b, wthid, b_hid, nullptr, h2b, H, H, 256);
  fb_end_kernel<<<B / 4, 256, 0, stream>>>(h2b, W_fb, b_fb, ns, eb, DI, SQDT);
  // bicep: eb @ wtagg^T + b_agg + h2 -> xb (combined), K=256
  gemm8<2><<<256, 512, 0, stream>>>(eb, wtagg, b_agg, h2b, xb, H, P, 256);
  // final: combined @ W_out^T + b_out -> fp32 d_out, K=1024
  gemm8<3><<<256, 512, 0, stream>>>(xb, wtout, b_out, nullptr, d_out, H, H, 256);
}